// Round 11
// baseline (68.073 us; speedup 1.0000x reference)
//
#include <hip/hip_runtime.h>
#include <hip/hip_bf16.h>

typedef float f32x4 __attribute__((ext_vector_type(4)));
typedef float f32x16 __attribute__((ext_vector_type(16)));
typedef short s16x8 __attribute__((ext_vector_type(8)));
typedef unsigned int u32x4 __attribute__((ext_vector_type(4)));

__device__ __forceinline__ short f2bf(float v) {
    __hip_bfloat16 h = __float2bfloat16(v);
    return __builtin_bit_cast(short, h);
}
__device__ __forceinline__ unsigned cvtpk(float lo, float hi) {
    unsigned r;
    asm("v_cvt_pk_bf16_f32 %0, %1, %2" : "=v"(r) : "v"(lo), "v"(hi));
    return r;
}
// v_permlane32_swap_b32: x <- {x_lo, y_lo}, y <- {x_hi, y_hi}
__device__ __forceinline__ void swap32(unsigned &x, unsigned &y) {
    asm("v_permlane32_swap_b32 %0, %1" : "+v"(x), "+v"(y));
}

// Kernel 1: xa[a][k] = b1[k] + sum_d x[a][d]*W1[d][k];  yb[b][k] = sum_d y[b][d]*W1[128+d][k]
__global__ __launch_bounds__(128) void precompute_kernel(
    const float* __restrict__ x, const float* __restrict__ y,
    const float* __restrict__ W1, const float* __restrict__ b1,
    float* __restrict__ xa, float* __restrict__ yb)
{
    __shared__ float rows[8][128];
    const int bid = blockIdx.x;
    const int k = threadIdx.x;
    const bool is_x = bid < 128;
    const int r0 = (is_x ? bid : bid - 128) * 8;
    const float* src = (is_x ? x : y) + (size_t)r0 * 128;
    const float* w = is_x ? W1 : (W1 + 128 * 128);
#pragma unroll
    for (int r = 0; r < 8; ++r) rows[r][k] = src[r * 128 + k];
    __syncthreads();
    float acc[8];
    const float bias = is_x ? b1[k] : 0.0f;
#pragma unroll
    for (int r = 0; r < 8; ++r) acc[r] = bias;
    for (int d = 0; d < 128; ++d) {
        float wv = w[d * 128 + k];
#pragma unroll
        for (int r = 0; r < 8; ++r) acc[r] = fmaf(rows[r][d], wv, acc[r]);
    }
    float* dst = (is_x ? xa : yb) + (size_t)r0 * 128 + k;
#pragma unroll
    for (int r = 0; r < 8; ++r) dst[r * 128] = acc[r];
}

// Builds the 8 layer-1 B-fragments for a-row AI into BUF (r5-validated math).
#define BUILD_FRAGS(BUF, AI)                                                   \
    {                                                                          \
        const float* xr_ = &xa_lds[(AI) * 128 + half * 8];                     \
        _Pragma("unroll")                                                      \
        for (int s_ = 0; s_ < 8; ++s_) {                                       \
            f32x4 x0_ = *(const f32x4*)&xr_[s_ * 16];                          \
            f32x4 x1_ = *(const f32x4*)&xr_[s_ * 16 + 4];                      \
            f32x4 h0_ = x0_ + yv0[s_];                                         \
            f32x4 h1_ = x1_ + yv1[s_];                                         \
            u32x4 q_;                                                          \
            q_.x = cvtpk(fmaxf(h0_.x, 0.f), fmaxf(h0_.y, 0.f));                \
            q_.y = cvtpk(fmaxf(h0_.z, 0.f), fmaxf(h0_.w, 0.f));                \
            q_.z = cvtpk(fmaxf(h1_.x, 0.f), fmaxf(h1_.y, 0.f));                \
            q_.w = cvtpk(fmaxf(h1_.z, 0.f), fmaxf(h1_.w, 0.f));                \
            BUF[s_] = __builtin_bit_cast(s16x8, q_);                           \
        }                                                                      \
    }

// One pipelined step: 16-MFMA L2 cluster on CUR; build NXT (next a-row) VALU is
// forced INTO the MFMA shadow by sched_group_barrier: [16 ds_read] then
// 16 x {1 MFMA, 10 VALU}. Pack/L3/L4 left unconstrained (dependency-ordered).
#define PIPE_STEP(CUR, NXT, AI)                                                \
    {                                                                          \
        f32x16 c20 = __builtin_amdgcn_mfma_f32_32x32x16_bf16(W2a[0][0], CUR[0], b2v0, 0, 0, 0); \
        f32x16 c21 = __builtin_amdgcn_mfma_f32_32x32x16_bf16(W2a[1][0], CUR[0], b2v1, 0, 0, 0); \
        _Pragma("unroll")                                                      \
        for (int s_ = 1; s_ < 8; ++s_) {                                       \
            c20 = __builtin_amdgcn_mfma_f32_32x32x16_bf16(W2a[0][s_], CUR[s_], c20, 0, 0, 0); \
            c21 = __builtin_amdgcn_mfma_f32_32x32x16_bf16(W2a[1][s_], CUR[s_], c21, 0, 0, 0); \
        }                                                                      \
        BUILD_FRAGS(NXT, ((AI) + 1) & 15)                                      \
        /* forced interleave: loads first, then 1 MFMA per 10 VALU */          \
        __builtin_amdgcn_sched_group_barrier(0x100, 16, 0);                    \
        _Pragma("unroll")                                                      \
        for (int g_ = 0; g_ < 16; ++g_) {                                      \
            __builtin_amdgcn_sched_group_barrier(0x008, 1, 0);                 \
            __builtin_amdgcn_sched_group_barrier(0x002, 10, 0);                \
        }                                                                      \
        unsigned P[8], Q[8];                                                   \
        _Pragma("unroll")                                                      \
        for (int i_ = 0; i_ < 8; ++i_) {                                       \
            P[i_] = cvtpk(fmaxf(c20[2 * i_], 0.f), fmaxf(c20[2 * i_ + 1], 0.f)); \
            Q[i_] = cvtpk(fmaxf(c21[2 * i_], 0.f), fmaxf(c21[2 * i_ + 1], 0.f)); \
        }                                                                      \
        s16x8 bf3[4];                                                          \
        {                                                                      \
            unsigned w0 = P[0], w2 = P[2]; swap32(w0, w2);                     \
            unsigned w1 = P[1], w3 = P[3]; swap32(w1, w3);                     \
            u32x4 t; t.x = w0; t.y = w1; t.z = w2; t.w = w3;                   \
            bf3[0] = __builtin_bit_cast(s16x8, t);                             \
            unsigned v0 = P[4], v2 = P[6]; swap32(v0, v2);                     \
            unsigned v1 = P[5], v3 = P[7]; swap32(v1, v3);                     \
            u32x4 u; u.x = v0; u.y = v1; u.z = v2; u.w = v3;                   \
            bf3[1] = __builtin_bit_cast(s16x8, u);                             \
            unsigned a0 = Q[0], a2 = Q[2]; swap32(a0, a2);                     \
            unsigned a1 = Q[1], a3 = Q[3]; swap32(a1, a3);                     \
            u32x4 t2; t2.x = a0; t2.y = a1; t2.z = a2; t2.w = a3;              \
            bf3[2] = __builtin_bit_cast(s16x8, t2);                            \
            unsigned e0 = Q[4], e2 = Q[6]; swap32(e0, e2);                     \
            unsigned e1 = Q[5], e3 = Q[7]; swap32(e1, e3);                     \
            u32x4 u2; u2.x = e0; u2.y = e1; u2.z = e2; u2.w = e3;              \
            bf3[3] = __builtin_bit_cast(s16x8, u2);                            \
        }                                                                      \
        f32x16 c3 = __builtin_amdgcn_mfma_f32_32x32x16_bf16(W3a[0], bf3[0], fz, 0, 0, 0); \
        _Pragma("unroll")                                                      \
        for (int s_ = 1; s_ < 4; ++s_)                                         \
            c3 = __builtin_amdgcn_mfma_f32_32x32x16_bf16(W3a[s_], bf3[s_], c3, 0, 0, 0); \
        float p = 0.f;                                                         \
        _Pragma("unroll")                                                      \
        for (int j_ = 0; j_ < 4; ++j_)                                         \
            p = fmaf(fmaxf(c3[j_] + b3v[j_], 0.f), w4v[j_], p);                \
        unsigned pu = __builtin_bit_cast(unsigned, p);                         \
        unsigned pv = pu;                                                      \
        asm("" : "+v"(pv));                                                    \
        swap32(pu, pv);                                                        \
        float r_ = __builtin_bit_cast(float, pu) + __builtin_bit_cast(float, pv) + b4s; \
        if (half == 0)                                                         \
            outp[(size_t)(AI) * 1024] = r_;                                    \
    }

// Kernel 2: fused pairwise MLP, 2-stage pipeline + forced MFMA/VALU interleave.
// Odd waves start the (order-independent) a-loop at ai=8 to break wave lockstep.
// Grid 512 x 256. a_chunk = bid>>3 (16 a's via LDS), wave b-group = (bid&7)*4+wave.
__global__ __launch_bounds__(256, 2) void fused_kernel(
    const float* __restrict__ xa, const float* __restrict__ yb,
    const float* __restrict__ W2, const float* __restrict__ b2,
    const float* __restrict__ W3, const float* __restrict__ b3,
    const float* __restrict__ W4, const float* __restrict__ b4,
    float* __restrict__ out)
{
    __shared__ float xa_lds[16 * 128];   // 8 KB

    const int tid = threadIdx.x;
    const int bid = blockIdx.x;
    const int a_chunk = bid >> 3;        // 0..63, 16 a's each
    const int bq = bid & 7;
    const int wave = tid >> 6;
    const int lane = tid & 63;
    const int half = lane >> 5;
    const int m = lane & 31;
    const int bg = bq * 4 + wave;        // 0..31

    // ---- stage xa tile (16 rows x 128 f32): two f32x4 per thread ----
    {
        const f32x4* xsrc = (const f32x4*)(xa + (size_t)a_chunk * 16 * 128);
        f32x4* dst = (f32x4*)xa_lds;
        dst[tid] = xsrc[tid];
        dst[tid + 256] = xsrc[tid + 256];
    }

    // ---- y row in B-fragment order (r1/r5 slot mapping), registers ----
    f32x4 yv0[8], yv1[8];
    {
        const float* yrow = yb + (size_t)(bg * 32 + m) * 128 + half * 8;
#pragma unroll
        for (int s = 0; s < 8; ++s) {
            yv0[s] = *(const f32x4*)&yrow[s * 16];
            yv1[s] = *(const f32x4*)&yrow[s * 16 + 4];
        }
    }

    // Layer2 A = W2^T: A[m'][k], m' = lane&31 (+32*mt), k = s*16 + half*8 + j
    s16x8 W2a[2][8];
#pragma unroll
    for (int mt = 0; mt < 2; ++mt)
#pragma unroll
        for (int s = 0; s < 8; ++s)
#pragma unroll
            for (int j = 0; j < 8; ++j)
                W2a[mt][s][j] = f2bf(W2[(s * 16 + half * 8 + j) * 64 + mt * 32 + m]);

    // Layer3 A = W3^T padded M 8->32 (registers, r5/r6-validated)
    s16x8 W3a[4];
#pragma unroll
    for (int s = 0; s < 4; ++s)
#pragma unroll
        for (int j = 0; j < 8; ++j)
            W3a[s][j] = (m < 8) ? f2bf(W3[(s * 16 + half * 8 + j) * 8 + m]) : (short)0;

    // b2 as C-operand registers (r5-validated); b3 folded into L4 (r6-validated)
    f32x16 b2v0, b2v1;
#pragma unroll
    for (int r = 0; r < 16; ++r) {
        int f = (r & 3) + 8 * (r >> 2) + 4 * half;
        b2v0[r] = b2[f];
        b2v1[r] = b2[f + 32];
    }
    const f32x16 fz = {};
    float b3v[4], w4v[4];
#pragma unroll
    for (int j = 0; j < 4; ++j) {
        b3v[j] = b3[j + 4 * half];
        w4v[j] = W4[j + 4 * half];
    }
    const float b4s = b4[0];

    __syncthreads();

    float* outp = out + (size_t)(a_chunk * 16) * 1024 + bg * 32 + m;

    // ---- 2-stage software pipeline over the 16 a-rows (staggered start) ----
    const int ai0 = (wave & 1) << 3;
    s16x8 bufA[8], bufB[8];
    BUILD_FRAGS(bufA, ai0)
    for (int i = 0; i < 16; i += 2) {
        PIPE_STEP(bufA, bufB, (ai0 + i) & 15)
        PIPE_STEP(bufB, bufA, (ai0 + i + 1) & 15)
    }
}

extern "C" void kernel_launch(void* const* d_in, const int* in_sizes, int n_in,
                              void* d_out, int out_size, void* d_ws, size_t ws_size,
                              hipStream_t stream) {
    const float* x  = (const float*)d_in[0];
    const float* y  = (const float*)d_in[1];
    const float* W1 = (const float*)d_in[2];
    const float* b1 = (const float*)d_in[3];
    const float* W2 = (const float*)d_in[4];
    const float* b2 = (const float*)d_in[5];
    const float* W3 = (const float*)d_in[6];
    const float* b3 = (const float*)d_in[7];
    const float* W4 = (const float*)d_in[8];
    const float* b4 = (const float*)d_in[9];
    float* out = (float*)d_out;

    float* xa = (float*)d_ws;              // 1024*128 f32
    float* yb = xa + 1024 * 128;           // 1024*128 f32

    precompute_kernel<<<dim3(256), dim3(128), 0, stream>>>(x, y, W1, b1, xa, yb);
    fused_kernel<<<dim3(512), dim3(256), 0, stream>>>(xa, yb, W2, b2, W3, b3, W4, b4, out);
}

// Round 12
// 40.248 us; speedup vs baseline: 1.6913x; 1.6913x over previous
//
#include <hip/hip_runtime.h>
#include <hip/hip_bf16.h>

typedef float f32x4 __attribute__((ext_vector_type(4)));
typedef float f32x16 __attribute__((ext_vector_type(16)));
typedef short s16x8 __attribute__((ext_vector_type(8)));
typedef unsigned int u32x4 __attribute__((ext_vector_type(4)));

__device__ __forceinline__ short f2bf(float v) {
    __hip_bfloat16 h = __float2bfloat16(v);
    return __builtin_bit_cast(short, h);
}
__device__ __forceinline__ unsigned cvtpk(float lo, float hi) {
    unsigned r;
    asm("v_cvt_pk_bf16_f32 %0, %1, %2" : "=v"(r) : "v"(lo), "v"(hi));
    return r;
}
// v_permlane32_swap_b32: x <- {x_lo, y_lo}, y <- {x_hi, y_hi}
__device__ __forceinline__ void swap32(unsigned &x, unsigned &y) {
    asm("v_permlane32_swap_b32 %0, %1" : "+v"(x), "+v"(y));
}

// Kernel 1: xa[a][k] = b1[k] + sum_d x[a][d]*W1[d][k];  yb[b][k] = sum_d y[b][d]*W1[128+d][k]
__global__ __launch_bounds__(128) void precompute_kernel(
    const float* __restrict__ x, const float* __restrict__ y,
    const float* __restrict__ W1, const float* __restrict__ b1,
    float* __restrict__ xa, float* __restrict__ yb)
{
    __shared__ float rows[8][128];
    const int bid = blockIdx.x;
    const int k = threadIdx.x;
    const bool is_x = bid < 128;
    const int r0 = (is_x ? bid : bid - 128) * 8;
    const float* src = (is_x ? x : y) + (size_t)r0 * 128;
    const float* w = is_x ? W1 : (W1 + 128 * 128);
#pragma unroll
    for (int r = 0; r < 8; ++r) rows[r][k] = src[r * 128 + k];
    __syncthreads();
    float acc[8];
    const float bias = is_x ? b1[k] : 0.0f;
#pragma unroll
    for (int r = 0; r < 8; ++r) acc[r] = bias;
    for (int d = 0; d < 128; ++d) {
        float wv = w[d * 128 + k];
#pragma unroll
        for (int r = 0; r < 8; ++r) acc[r] = fmaf(rows[r][d], wv, acc[r]);
    }
    float* dst = (is_x ? xa : yb) + (size_t)r0 * 128 + k;
#pragma unroll
    for (int r = 0; r < 8; ++r) dst[r * 128] = acc[r];
}

// Kernel 2: fused pairwise MLP. r5-validated datapath, TWO independent a-rows
// per iteration (rows ai and ai+8): 4 independent L2 chains + 2 L3 chains in
// flight, zero merge cost. b2/b3 C-inits and W3 fragments come from LDS
// (r8-validated mappings) to pay for the second accumulator set.
// Grid 512 x 256. a_chunk = bid>>3 (16 a's via LDS), wave b-group = (bid&7)*4+wave.
__global__ __launch_bounds__(256, 2) void fused_kernel(
    const float* __restrict__ xa, const float* __restrict__ yb,
    const float* __restrict__ W2, const float* __restrict__ b2,
    const float* __restrict__ W3, const float* __restrict__ b3,
    const float* __restrict__ W4, const float* __restrict__ b4,
    float* __restrict__ out)
{
    __shared__ float xa_lds[16 * 128];                      // 8 KB
    __shared__ __align__(16) short w3_lds[4 * 64 * 8];      // 4 KB: [s][lane][8]
    __shared__ __align__(64) float b2_lds[64];              // [mt][half][16] C-layout
    __shared__ __align__(64) float b3_lds[32];              // [half][16] C-layout (r>=4 zero)

    const int tid = threadIdx.x;
    const int bid = blockIdx.x;
    const int a_chunk = bid >> 3;        // 0..63, 16 a's each
    const int bq = bid & 7;
    const int wave = tid >> 6;
    const int lane = tid & 63;
    const int half = lane >> 5;
    const int m = lane & 31;
    const int bg = bq * 4 + wave;        // 0..31

    // ---- stage xa tile (16 rows x 128 f32): two f32x4 per thread ----
    {
        const f32x4* xsrc = (const f32x4*)(xa + (size_t)a_chunk * 16 * 128);
        f32x4* dst = (f32x4*)xa_lds;
        dst[tid] = xsrc[tid];
        dst[tid + 256] = xsrc[tid + 256];
    }
    // ---- W3 fragment table (M padded 8->32), r8-validated ----
    {
        int l = tid & 63, s = tid >> 6;
        int row = l & 31;
        int krow = s * 16 + (l >> 5) * 8;
        u32x4 q;
#pragma unroll
        for (int jj = 0; jj < 4; ++jj) {
            float lo = (row < 8) ? W3[(krow + 2 * jj) * 8 + row] : 0.f;
            float hi = (row < 8) ? W3[(krow + 2 * jj + 1) * 8 + row] : 0.f;
            q[jj] = cvtpk(lo, hi);
        }
        *(u32x4*)&w3_lds[tid * 8] = q;
    }
    // ---- bias C-init tables (r8-validated) ----
    if (tid < 64)
        b2_lds[tid] = b2[(tid & 3) + 8 * ((tid >> 2) & 3) + 4 * ((tid >> 4) & 1) + 32 * (tid >> 5)];
    if (tid < 32)
        b3_lds[tid] = ((tid & 15) < 4) ? b3[(tid & 3) + 4 * (tid >> 4)] : 0.f;

    // ---- y row in B-fragment order (r1/r5 slot mapping), registers ----
    f32x4 yv0[8], yv1[8];
    {
        const float* yrow = yb + (size_t)(bg * 32 + m) * 128 + half * 8;
#pragma unroll
        for (int s = 0; s < 8; ++s) {
            yv0[s] = *(const f32x4*)&yrow[s * 16];
            yv1[s] = *(const f32x4*)&yrow[s * 16 + 4];
        }
    }

    // Layer2 A = W2^T: A[m'][k], m' = lane&31 (+32*mt), k = s*16 + half*8 + j
    s16x8 W2a[2][8];
#pragma unroll
    for (int mt = 0; mt < 2; ++mt)
#pragma unroll
        for (int s = 0; s < 8; ++s)
#pragma unroll
            for (int j = 0; j < 8; ++j)
                W2a[mt][s][j] = f2bf(W2[(s * 16 + half * 8 + j) * 64 + mt * 32 + m]);

    float w4v[4];
#pragma unroll
    for (int j = 0; j < 4; ++j) w4v[j] = W4[j + 4 * half];
    const float b4s = b4[0];

    __syncthreads();

    const short* w3p = &w3_lds[lane * 8];
    float* outp = out + (size_t)(a_chunk * 16) * 1024 + bg * 32 + m;

    for (int ai = 0; ai < 8; ++ai) {
        // ---- build layer-1 B-fragments for BOTH rows (ai and ai+8) ----
        s16x8 bfrA[8], bfrB[8];
        {
            const float* xrA = &xa_lds[ai * 128 + half * 8];
            const float* xrB = &xa_lds[(ai + 8) * 128 + half * 8];
#pragma unroll
            for (int s = 0; s < 8; ++s) {
                f32x4 a0 = *(const f32x4*)&xrA[s * 16] + yv0[s];
                f32x4 a1 = *(const f32x4*)&xrA[s * 16 + 4] + yv1[s];
                u32x4 qa;
                qa.x = cvtpk(fmaxf(a0.x, 0.f), fmaxf(a0.y, 0.f));
                qa.y = cvtpk(fmaxf(a0.z, 0.f), fmaxf(a0.w, 0.f));
                qa.z = cvtpk(fmaxf(a1.x, 0.f), fmaxf(a1.y, 0.f));
                qa.w = cvtpk(fmaxf(a1.z, 0.f), fmaxf(a1.w, 0.f));
                bfrA[s] = __builtin_bit_cast(s16x8, qa);
                f32x4 b0 = *(const f32x4*)&xrB[s * 16] + yv0[s];
                f32x4 b1 = *(const f32x4*)&xrB[s * 16 + 4] + yv1[s];
                u32x4 qb;
                qb.x = cvtpk(fmaxf(b0.x, 0.f), fmaxf(b0.y, 0.f));
                qb.y = cvtpk(fmaxf(b0.z, 0.f), fmaxf(b0.w, 0.f));
                qb.z = cvtpk(fmaxf(b1.x, 0.f), fmaxf(b1.y, 0.f));
                qb.w = cvtpk(fmaxf(b1.z, 0.f), fmaxf(b1.w, 0.f));
                bfrB[s] = __builtin_bit_cast(s16x8, qb);
            }
        }

        // ---- 4 independent L2 chains (b2 C-init from LDS, r8-validated) ----
        const f32x16 cb0 = *(const f32x16*)&b2_lds[half * 16];
        const f32x16 cb1 = *(const f32x16*)&b2_lds[32 + half * 16];
        f32x16 c20A = __builtin_amdgcn_mfma_f32_32x32x16_bf16(W2a[0][0], bfrA[0], cb0, 0, 0, 0);
        f32x16 c21A = __builtin_amdgcn_mfma_f32_32x32x16_bf16(W2a[1][0], bfrA[0], cb1, 0, 0, 0);
        f32x16 c20B = __builtin_amdgcn_mfma_f32_32x32x16_bf16(W2a[0][0], bfrB[0], cb0, 0, 0, 0);
        f32x16 c21B = __builtin_amdgcn_mfma_f32_32x32x16_bf16(W2a[1][0], bfrB[0], cb1, 0, 0, 0);
#pragma unroll
        for (int s = 1; s < 8; ++s) {
            c20A = __builtin_amdgcn_mfma_f32_32x32x16_bf16(W2a[0][s], bfrA[s], c20A, 0, 0, 0);
            c21A = __builtin_amdgcn_mfma_f32_32x32x16_bf16(W2a[1][s], bfrA[s], c21A, 0, 0, 0);
            c20B = __builtin_amdgcn_mfma_f32_32x32x16_bf16(W2a[0][s], bfrB[s], c20B, 0, 0, 0);
            c21B = __builtin_amdgcn_mfma_f32_32x32x16_bf16(W2a[1][s], bfrB[s], c21B, 0, 0, 0);
        }

        // ---- pack + swaps, row A then row B (validated r1/r3/r5) ----
        s16x8 bf3A[4], bf3B[4];
        {
            unsigned P[8], Q[8];
#pragma unroll
            for (int i = 0; i < 8; ++i) {
                P[i] = cvtpk(fmaxf(c20A[2 * i], 0.f), fmaxf(c20A[2 * i + 1], 0.f));
                Q[i] = cvtpk(fmaxf(c21A[2 * i], 0.f), fmaxf(c21A[2 * i + 1], 0.f));
            }
            unsigned w0 = P[0], w2 = P[2]; swap32(w0, w2);
            unsigned w1 = P[1], w3 = P[3]; swap32(w1, w3);
            u32x4 t; t.x = w0; t.y = w1; t.z = w2; t.w = w3;
            bf3A[0] = __builtin_bit_cast(s16x8, t);
            unsigned v0 = P[4], v2 = P[6]; swap32(v0, v2);
            unsigned v1 = P[5], v3 = P[7]; swap32(v1, v3);
            u32x4 u; u.x = v0; u.y = v1; u.z = v2; u.w = v3;
            bf3A[1] = __builtin_bit_cast(s16x8, u);
            unsigned a0 = Q[0], a2 = Q[2]; swap32(a0, a2);
            unsigned a1 = Q[1], a3 = Q[3]; swap32(a1, a3);
            u32x4 t2; t2.x = a0; t2.y = a1; t2.z = a2; t2.w = a3;
            bf3A[2] = __builtin_bit_cast(s16x8, t2);
            unsigned e0 = Q[4], e2 = Q[6]; swap32(e0, e2);
            unsigned e1 = Q[5], e3 = Q[7]; swap32(e1, e3);
            u32x4 u2; u2.x = e0; u2.y = e1; u2.z = e2; u2.w = e3;
            bf3A[3] = __builtin_bit_cast(s16x8, u2);
        }
        {
            unsigned P[8], Q[8];
#pragma unroll
            for (int i = 0; i < 8; ++i) {
                P[i] = cvtpk(fmaxf(c20B[2 * i], 0.f), fmaxf(c20B[2 * i + 1], 0.f));
                Q[i] = cvtpk(fmaxf(c21B[2 * i], 0.f), fmaxf(c21B[2 * i + 1], 0.f));
            }
            unsigned w0 = P[0], w2 = P[2]; swap32(w0, w2);
            unsigned w1 = P[1], w3 = P[3]; swap32(w1, w3);
            u32x4 t; t.x = w0; t.y = w1; t.z = w2; t.w = w3;
            bf3B[0] = __builtin_bit_cast(s16x8, t);
            unsigned v0 = P[4], v2 = P[6]; swap32(v0, v2);
            unsigned v1 = P[5], v3 = P[7]; swap32(v1, v3);
            u32x4 u; u.x = v0; u.y = v1; u.z = v2; u.w = v3;
            bf3B[1] = __builtin_bit_cast(s16x8, u);
            unsigned a0 = Q[0], a2 = Q[2]; swap32(a0, a2);
            unsigned a1 = Q[1], a3 = Q[3]; swap32(a1, a3);
            u32x4 t2; t2.x = a0; t2.y = a1; t2.z = a2; t2.w = a3;
            bf3B[2] = __builtin_bit_cast(s16x8, t2);
            unsigned e0 = Q[4], e2 = Q[6]; swap32(e0, e2);
            unsigned e1 = Q[5], e3 = Q[7]; swap32(e1, e3);
            u32x4 u2; u2.x = e0; u2.y = e1; u2.z = e2; u2.w = e3;
            bf3B[3] = __builtin_bit_cast(s16x8, u2);
        }

        // ---- 2 independent L3 chains (W3 frags + b3 C-init from LDS, r8-validated) ----
        const f32x16 c3i = *(const f32x16*)&b3_lds[half * 16];
        const s16x8 w3f0 = *(const s16x8*)(w3p + 0 * 512);
        const s16x8 w3f1 = *(const s16x8*)(w3p + 1 * 512);
        const s16x8 w3f2 = *(const s16x8*)(w3p + 2 * 512);
        const s16x8 w3f3 = *(const s16x8*)(w3p + 3 * 512);
        f32x16 c3A = __builtin_amdgcn_mfma_f32_32x32x16_bf16(w3f0, bf3A[0], c3i, 0, 0, 0);
        f32x16 c3B = __builtin_amdgcn_mfma_f32_32x32x16_bf16(w3f0, bf3B[0], c3i, 0, 0, 0);
        c3A = __builtin_amdgcn_mfma_f32_32x32x16_bf16(w3f1, bf3A[1], c3A, 0, 0, 0);
        c3B = __builtin_amdgcn_mfma_f32_32x32x16_bf16(w3f1, bf3B[1], c3B, 0, 0, 0);
        c3A = __builtin_amdgcn_mfma_f32_32x32x16_bf16(w3f2, bf3A[2], c3A, 0, 0, 0);
        c3B = __builtin_amdgcn_mfma_f32_32x32x16_bf16(w3f2, bf3B[2], c3B, 0, 0, 0);
        c3A = __builtin_amdgcn_mfma_f32_32x32x16_bf16(w3f3, bf3A[3], c3A, 0, 0, 0);
        c3B = __builtin_amdgcn_mfma_f32_32x32x16_bf16(w3f3, bf3B[3], c3B, 0, 0, 0);

        // ---- layer 4 + cross-half combine + store, both rows ----
        float pA = fmaxf(c3A[0], 0.f) * w4v[0] + fmaxf(c3A[1], 0.f) * w4v[1]
                 + fmaxf(c3A[2], 0.f) * w4v[2] + fmaxf(c3A[3], 0.f) * w4v[3];
        float pB = fmaxf(c3B[0], 0.f) * w4v[0] + fmaxf(c3B[1], 0.f) * w4v[1]
                 + fmaxf(c3B[2], 0.f) * w4v[2] + fmaxf(c3B[3], 0.f) * w4v[3];
        unsigned puA = __builtin_bit_cast(unsigned, pA);
        unsigned pvA = puA;
        asm("" : "+v"(pvA));
        swap32(puA, pvA);
        unsigned puB = __builtin_bit_cast(unsigned, pB);
        unsigned pvB = puB;
        asm("" : "+v"(pvB));
        swap32(puB, pvB);
        float rA = __builtin_bit_cast(float, puA) + __builtin_bit_cast(float, pvA) + b4s;
        float rB = __builtin_bit_cast(float, puB) + __builtin_bit_cast(float, pvB) + b4s;
        if (half == 0) {
            outp[(size_t)ai * 1024] = rA;
            outp[(size_t)(ai + 8) * 1024] = rB;
        }
    }
}

extern "C" void kernel_launch(void* const* d_in, const int* in_sizes, int n_in,
                              void* d_out, int out_size, void* d_ws, size_t ws_size,
                              hipStream_t stream) {
    const float* x  = (const float*)d_in[0];
    const float* y  = (const float*)d_in[1];
    const float* W1 = (const float*)d_in[2];
    const float* b1 = (const float*)d_in[3];
    const float* W2 = (const float*)d_in[4];
    const float* b2 = (const float*)d_in[5];
    const float* W3 = (const float*)d_in[6];
    const float* b3 = (const float*)d_in[7];
    const float* W4 = (const float*)d_in[8];
    const float* b4 = (const float*)d_in[9];
    float* out = (float*)d_out;

    float* xa = (float*)d_ws;              // 1024*128 f32
    float* yb = xa + 1024 * 128;           // 1024*128 f32

    precompute_kernel<<<dim3(256), dim3(128), 0, stream>>>(x, y, W1, b1, xa, yb);
    fused_kernel<<<dim3(512), dim3(256), 0, stream>>>(xa, yb, W2, b2, W3, b3, W4, b4, out);
}